// Round 20
// baseline (1247.468 us; speedup 1.0000x reference)
//
#include <hip/hip_runtime.h>
#include <hip/hip_bf16.h>
#include <math.h>

using bf16 = __hip_bfloat16;
typedef __attribute__((ext_vector_type(8))) short short8;
typedef __attribute__((ext_vector_type(4))) float f32x4;
typedef __attribute__((ext_vector_type(16))) float f32x16;

#define NSEQ   577
#define NBATCH 64
#define NTOK   36928   // 64*577
#define MPAD   37120   // NTOK padded to multiple of 256
#define NHEADS 12
#define HDIM   64
#define NP     640     // padded seq len (multiple of 128)
#define CEMB   768
#define CHID   3072
#define NBH    (NBATCH*NHEADS)   // 768 head instances

__device__ __forceinline__ bf16 f2bf(float v){ return __float2bfloat16(v); }

// tanh-form GELU via one __expf; |err| vs exact ~1e-3, below bf16 rounding here.
__device__ __forceinline__ float gelu_f(float x) {
    float x3 = x * x * x;
    float y = 1.5957691216057308f * (x + 0.044715f * x3);
    float e = __expf(y);
    float t = 1.0f - 2.0f / (e + 1.0f);
    return 0.5f * x * (1.0f + t);
}

#define GLOAD_LDS16(gaddr, laddr) \
  __builtin_amdgcn_global_load_lds((__attribute__((address_space(1))) const void*)(gaddr), \
                                   (__attribute__((address_space(3))) void*)(laddr), 16, 0, 0)

// ---------------- weight convert+transpose: src fp32 [R][C] -> dst bf16 [C][R]
__global__ __launch_bounds__(256) void transpose_w(const float* __restrict__ src,
                                                   bf16* __restrict__ dst, int R, int C) {
    long idx = (long)blockIdx.x * 256 + threadIdx.x;
    long total = (long)R * C;
    if (idx < total) {
        int r = (int)(idx / C);
        int c = (int)(idx - (long)r * C);
        dst[(long)c * R + r] = f2bf(src[idx]);
    }
}

// ---------------- LayerNorm: fp32 [rows][768] -> bf16 [rows][768]
__global__ __launch_bounds__(256) void ln_kernel(const float* __restrict__ x,
                                                 const float* __restrict__ gamma,
                                                 const float* __restrict__ beta,
                                                 bf16* __restrict__ out) {
    int row = blockIdx.x;
    const float* xr = x + (size_t)row * CEMB;
    int tid = threadIdx.x;
    float v0 = xr[tid], v1 = xr[tid + 256], v2 = xr[tid + 512];
    float s = v0 + v1 + v2;
    #pragma unroll
    for (int o = 32; o > 0; o >>= 1) s += __shfl_down(s, o);
    __shared__ float red[4];
    if ((tid & 63) == 0) red[tid >> 6] = s;
    __syncthreads();
    float mean = (red[0] + red[1] + red[2] + red[3]) * (1.0f / CEMB);
    float d0 = v0 - mean, d1 = v1 - mean, d2 = v2 - mean;
    float q = d0*d0 + d1*d1 + d2*d2;
    #pragma unroll
    for (int o = 32; o > 0; o >>= 1) q += __shfl_down(q, o);
    __shared__ float red2[4];
    if ((tid & 63) == 0) red2[tid >> 6] = q;
    __syncthreads();
    float var = (red2[0] + red2[1] + red2[2] + red2[3]) * (1.0f / CEMB);
    float rs = rsqrtf(var + 1e-5f);
    bf16* orow = out + (size_t)row * CEMB;
    orow[tid]       = f2bf(d0 * rs * gamma[tid]       + beta[tid]);
    orow[tid + 256] = f2bf(d1 * rs * gamma[tid + 256] + beta[tid + 256]);
    orow[tid + 512] = f2bf(d2 * rs * gamma[tid + 512] + beta[tid + 512]);
}

// ---------------- fused flash attention (r17/r19 version, unchanged) ----------
__global__ __launch_bounds__(256) void flash_attn(const bf16* __restrict__ qg,
                                                  const bf16* __restrict__ kg,
                                                  const bf16* __restrict__ vtg,
                                                  bf16* __restrict__ og) {
    const int tid = threadIdx.x, lane = tid & 63, w = tid >> 6;
    const int fr = lane & 15, fh = lane >> 4;

    const int QB = NP / 128;
    const int nwg = QB * NBH;
    const int lin = blockIdx.y * QB + blockIdx.x;
    const int qq = nwg >> 3;
    const int lin2 = (lin & 7) * qq + (lin >> 3);
    const int bh = lin2 / QB;
    const int q0 = (lin2 - bh * QB) * 128;
    const int wr = w * 32;

    __shared__ bf16 Ks[2][64 * 64];
    __shared__ bf16 Vs[2][64 * 64];
    __shared__ bf16 Ps[128 * 64];

    const bf16* qb = qg  + (size_t)bh * NP * HDIM;
    const bf16* kb = kg  + (size_t)bh * NP * HDIM;
    const bf16* vb = vtg + (size_t)bh * HDIM * NP;

    const int swz  = (fr & 7) << 3;
    const int scol = (((lane & 7) ^ (lane >> 3)) << 3);
    const int srow = lane >> 3;

    short8 qa[2][2];
    #pragma unroll
    for (int mi = 0; mi < 2; mi++)
        #pragma unroll
        for (int ks = 0; ks < 2; ks++)
            qa[mi][ks] = *reinterpret_cast<const short8*>(
                qb + (size_t)(q0 + wr + mi * 16 + fr) * HDIM + ks * 32 + fh * 8);
    #pragma unroll
    for (int mi = 0; mi < 2; mi++)
        #pragma unroll
        for (int ks = 0; ks < 2; ks++)
            asm volatile("" : "+v"(qa[mi][ks]));

    f32x4 od[2][4] = {};
    float m_run[2] = {-1e30f, -1e30f};
    float l_run[2] = {0.f, 0.f};

    auto stageKV = [&](int buf, int kb0) {
        GLOAD_LDS16(kb + (size_t)(kb0 + w * 8 + srow) * HDIM + scol,      Ks[buf] + w * 512);
        GLOAD_LDS16(kb + (size_t)(kb0 + 32 + w * 8 + srow) * HDIM + scol, Ks[buf] + 2048 + w * 512);
        GLOAD_LDS16(vb + (size_t)(w * 8 + srow) * NP + kb0 + scol,        Vs[buf] + w * 512);
        GLOAD_LDS16(vb + (size_t)(32 + w * 8 + srow) * NP + kb0 + scol,   Vs[buf] + 2048 + w * 512);
    };

    auto tileBody = [&](int buf, int kb0) {
        f32x4 sacc[2][4] = {};
        short8 kf[4][2];
        #pragma unroll
        for (int n = 0; n < 4; n++)
            #pragma unroll
            for (int ks = 0; ks < 2; ks++)
                kf[n][ks] = *reinterpret_cast<const short8*>(
                    &Ks[buf][(n * 16 + fr) * 64 + ((ks * 32 + fh * 8) ^ swz)]);
        __builtin_amdgcn_s_setprio(1);
        #pragma unroll
        for (int mi = 0; mi < 2; mi++)
            #pragma unroll
            for (int n = 0; n < 4; n++)
                #pragma unroll
                for (int ks = 0; ks < 2; ks++)
                    sacc[mi][n] = __builtin_amdgcn_mfma_f32_16x16x32_bf16(kf[n][ks], qa[mi][ks], sacc[mi][n], 0, 0, 0);
        __builtin_amdgcn_s_setprio(0);

        #pragma unroll
        for (int mi = 0; mi < 2; mi++) {
            float sv[4][4];
            float tm = -1e30f;
            #pragma unroll
            for (int n = 0; n < 4; n++)
                #pragma unroll
                for (int r = 0; r < 4; r++) {
                    int key = kb0 + n * 16 + fh * 4 + r;
                    float s = sacc[mi][n][r];
                    sv[n][r] = (key < NSEQ) ? s : -1e30f;
                    tm = fmaxf(tm, sv[n][r]);
                }
            tm = fmaxf(tm, __shfl_xor(tm, 16));
            tm = fmaxf(tm, __shfl_xor(tm, 32));
            float mo = m_run[mi];
            if (__any(tm - mo > 8.f)) {
                float mn = fmaxf(mo, tm);
                float sc = __expf(mo - mn);
                m_run[mi] = mn;
                l_run[mi] *= sc;
                #pragma unroll
                for (int r = 0; r < 4; r++) {
                    float s2 = __shfl(sc, fh * 4 + r);
                    #pragma unroll
                    for (int n2 = 0; n2 < 4; n2++) od[mi][n2][r] *= s2;
                }
                mo = mn;
            }
            float ps = 0.f;
            #pragma unroll
            for (int n = 0; n < 4; n++)
                #pragma unroll
                for (int r = 0; r < 4; r++) {
                    float e = __expf(sv[n][r] - mo);
                    sv[n][r] = e; ps += e;
                }
            ps += __shfl_xor(ps, 16);
            ps += __shfl_xor(ps, 32);
            l_run[mi] += ps;
            const int q = wr + mi * 16 + fr;
            char* prow = (char*)(Ps + q * 64);
            #pragma unroll
            for (int n = 0; n < 4; n++) {
                bf16 b0 = f2bf(sv[n][0]), b1 = f2bf(sv[n][1]);
                bf16 b2 = f2bf(sv[n][2]), b3 = f2bf(sv[n][3]);
                unsigned int lo = (unsigned int)*(unsigned short*)&b0 |
                                  ((unsigned int)*(unsigned short*)&b1 << 16);
                unsigned int hi = (unsigned int)*(unsigned short*)&b2 |
                                  ((unsigned int)*(unsigned short*)&b3 << 16);
                int chunk = (2 * n + (fh >> 1)) ^ (fr & 7);
                uint2 pk; pk.x = lo; pk.y = hi;
                *reinterpret_cast<uint2*>(prow + (chunk << 4) + ((fh & 1) << 3)) = pk;
            }
        }
        asm volatile("s_waitcnt lgkmcnt(0)" ::: "memory");
        __builtin_amdgcn_sched_barrier(0);

        short8 pa[2][2], vf[4][2];
        #pragma unroll
        for (int mi = 0; mi < 2; mi++)
            #pragma unroll
            for (int ks = 0; ks < 2; ks++)
                pa[mi][ks] = *reinterpret_cast<const short8*>(
                    &Ps[(wr + mi * 16 + fr) * 64 + ((ks * 32 + fh * 8) ^ swz)]);
        #pragma unroll
        for (int n2 = 0; n2 < 4; n2++)
            #pragma unroll
            for (int ks = 0; ks < 2; ks++)
                vf[n2][ks] = *reinterpret_cast<const short8*>(
                    &Vs[buf][(n2 * 16 + fr) * 64 + ((ks * 32 + fh * 8) ^ swz)]);
        __builtin_amdgcn_s_setprio(1);
        #pragma unroll
        for (int mi = 0; mi < 2; mi++)
            #pragma unroll
            for (int n2 = 0; n2 < 4; n2++)
                #pragma unroll
                for (int ks = 0; ks < 2; ks++)
                    od[mi][n2] = __builtin_amdgcn_mfma_f32_16x16x32_bf16(pa[mi][ks], vf[n2][ks], od[mi][n2], 0, 0, 0);
        __builtin_amdgcn_s_setprio(0);
    };

    stageKV(0, 0);
    stageKV(1, 64);
    for (int t = 0; t < 9; ++t) {
        asm volatile("s_waitcnt vmcnt(4)" ::: "memory");
        __builtin_amdgcn_s_barrier();
        tileBody(t & 1, t * 64);
        asm volatile("s_waitcnt lgkmcnt(0)" ::: "memory");
        __builtin_amdgcn_s_barrier();
        if (t + 2 < 10) stageKV(t & 1, (t + 2) * 64);
    }
    asm volatile("s_waitcnt vmcnt(0)" ::: "memory");
    __builtin_amdgcn_s_barrier();
    tileBody(1, 9 * 64);

    const int b = bh / NHEADS, hh = bh - b * NHEADS;
    #pragma unroll
    for (int mi = 0; mi < 2; mi++)
        #pragma unroll
        for (int r = 0; r < 4; r++) {
            float lv = __shfl(l_run[mi], fh * 4 + r);
            int qrow = q0 + wr + mi * 16 + fh * 4 + r;
            if (qrow < NSEQ) {
                float inv = 1.f / lv;
                #pragma unroll
                for (int n2 = 0; n2 < 4; n2++)
                    og[((size_t)(b * NSEQ + qrow)) * CEMB + hh * HDIM + n2 * 16 + fr] =
                        f2bf(od[mi][n2][r] * inv);
            }
        }
}

// ---------------- 256x128 tile, BK=32, 8 waves (4Mx2N), 2-phase 48KB dbuf
// r17 pipeline + 32x32x16 MFMA (fastest measured: 2495 TF vs 2176, half the
// instruction count at identical LDS traffic). C/D map: col=lane&31,
// row=(reg&3)+8*(reg>>2)+4*(lane>>5) (HW-verified m74/m101).
#define MODE_QKV  1
#define MODE_PROJ 3
#define MODE_FC1  4
#define MODE_FC2  5

struct GemmParams {
    const bf16* A;
    const bf16* Bt;
    int M, N, K;            // M %256==0, N %128==0; K%32==0
    int Mreal;
    float* Cf;
    bf16* Cb;
    const float* bias;
    const float* resid;
    bf16* qb; bf16* kb; bf16* vtb;
};

template<int MODE>
__global__ __launch_bounds__(512, 2) void gemm256(GemmParams p) {
    __shared__ bf16 As[2][256 * 32];   // 16 KB each, swizzle key (row>>1)&3
    __shared__ bf16 Bs[2][128 * 32];   // 8 KB each
    const int tid  = threadIdx.x;
    const int lane = tid & 63;

    const int gx = gridDim.x, gy = gridDim.y;
    const int nwg = gx * gy;
    const int orig = blockIdx.y * gx + blockIdx.x;
    const int q8 = nwg >> 3, r8 = nwg & 7;
    const int xcd = orig & 7, oid = orig >> 3;
    const int lin2 = ((xcd < r8) ? xcd * (q8 + 1) : r8 * (q8 + 1) + (xcd - r8) * q8) + oid;
    const int bm = (lin2 / gy) * 256;
    const int bn = (lin2 % gy) * 128;

    const int Kd = p.K;
    const int w  = tid >> 6;
    const int wm = w >> 1, wn = w & 1;   // 4M x 2N wave grid, per-wave 64x64
    const int wr = wm * 64, wc = wn * 64;
    const int l31 = lane & 31;           // 32x32 fragment row/col
    const int kh  = lane >> 5;           // k-half selector
    const int kx  = (l31 >> 1) & 3;      // swizzle key of this lane's row (wave-uniform over m,ks)

    const int srowA = tid >> 2;
    const int scol  = (((tid & 3) ^ ((tid >> 3) & 3)) << 3);
    const bf16* aS0 = p.A  + (size_t)(bm + srowA) * Kd + scol;
    const bf16* aS1 = p.A  + (size_t)(bm + 128 + srowA) * Kd + scol;
    const bf16* bS  = p.Bt + (size_t)(bn + srowA) * Kd + scol;

    f32x16 acc[2][2] = {};

    auto stage = [&](int buf, int kt) {
        GLOAD_LDS16(aS0 + (size_t)kt * 32, As[buf] + (size_t)tid * 8);
        GLOAD_LDS16(aS1 + (size_t)kt * 32, As[buf] + (size_t)(tid + 512) * 8);
        GLOAD_LDS16(bS  + (size_t)kt * 32, Bs[buf] + (size_t)tid * 8);
    };
    auto compute = [&](int buf) {
        const bf16* Ad = As[buf]; const bf16* Bd = Bs[buf];
        short8 a[2][2], b[2][2];
        #pragma unroll
        for (int ks = 0; ks < 2; ks++) {
            const int co = ((ks * 2 + kh) ^ kx) << 3;   // phys elem offset (16B chunk)
            #pragma unroll
            for (int n = 0; n < 2; n++)
                b[n][ks] = *reinterpret_cast<const short8*>(&Bd[(wc + n * 32 + l31) * 32 + co]);
            #pragma unroll
            for (int m = 0; m < 2; m++)
                a[m][ks] = *reinterpret_cast<const short8*>(&Ad[(wr + m * 32 + l31) * 32 + co]);
        }
        __builtin_amdgcn_s_setprio(1);
        #pragma unroll
        for (int m = 0; m < 2; m++)
            #pragma unroll
            for (int n = 0; n < 2; n++)
                #pragma unroll
                for (int ks = 0; ks < 2; ks++)
                    acc[m][n] = __builtin_amdgcn_mfma_f32_32x32x16_bf16(a[m][ks], b[n][ks], acc[m][n], 0, 0, 0);
        __builtin_amdgcn_s_setprio(0);
    };

    const int T = Kd >> 5;
    stage(0, 0);
    __syncthreads();
    for (int t = 1; t < T; ++t) {
        stage(t & 1, t);
        compute((t - 1) & 1);
        __syncthreads();
    }
    compute((T - 1) & 1);

    const int colw = bn + wc;

    if (MODE == MODE_QKV) {
        const int which = colw / CEMB;
        const int hh = (colw - which * CEMB) >> 6;
        const float scl = (which == 0) ? 0.125f : 1.0f;
        #pragma unroll
        for (int m = 0; m < 2; m++)
        #pragma unroll
        for (int reg = 0; reg < 16; reg++) {
            int row = bm + wr + m * 32 + (reg & 3) + 8 * (reg >> 2) + 4 * kh;
            if (row < p.Mreal) {
                int b2 = row / NSEQ;
                int n2 = row - b2 * NSEQ;
                size_t bh = (size_t)b2 * NHEADS + hh;
                if (which == 0) {
                    bf16* dst = p.qb + (bh * NP + n2) * HDIM + l31;
                    #pragma unroll
                    for (int n = 0; n < 2; n++) dst[n * 32] = f2bf(acc[m][n][reg] * scl);
                } else if (which == 1) {
                    bf16* dst = p.kb + (bh * NP + n2) * HDIM + l31;
                    #pragma unroll
                    for (int n = 0; n < 2; n++) dst[n * 32] = f2bf(acc[m][n][reg]);
                } else {
                    bf16* dst = p.vtb + (bh * HDIM + l31) * NP + n2;
                    #pragma unroll
                    for (int n = 0; n < 2; n++) dst[(size_t)n * 32 * NP] = f2bf(acc[m][n][reg]);
                }
            }
        }
    } else if (MODE == MODE_FC1) {
        const float* bp = p.bias + colw + l31;
        float bb[2];
        #pragma unroll
        for (int n = 0; n < 2; n++) bb[n] = bp[n * 32];
        #pragma unroll
        for (int m = 0; m < 2; m++)
        #pragma unroll
        for (int reg = 0; reg < 16; reg++) {
            int row = bm + wr + m * 32 + (reg & 3) + 8 * (reg >> 2) + 4 * kh;
            if (row < p.Mreal) {
                bf16* crow = p.Cb + (size_t)row * p.N + colw + l31;
                #pragma unroll
                for (int n = 0; n < 2; n++)
                    crow[n * 32] = f2bf(gelu_f(acc[m][n][reg] + bb[n]));
            }
        }
    } else {
        const float* bp = p.bias + colw + l31;
        float bb[2];
        #pragma unroll
        for (int n = 0; n < 2; n++) bb[n] = bp[n * 32];
        #pragma unroll
        for (int m = 0; m < 2; m++)
        #pragma unroll
        for (int reg = 0; reg < 16; reg++) {
            int row = bm + wr + m * 32 + (reg & 3) + 8 * (reg >> 2) + 4 * kh;
            if (row < p.Mreal) {
                float* crow = p.Cf + (size_t)row * p.N + colw + l31;
                const float* rrow = p.resid + (size_t)row * p.N + colw + l31;
                #pragma unroll
                for (int n = 0; n < 2; n++)
                    crow[n * 32] = acc[m][n][reg] + bb[n] + rrow[n * 32];
            }
        }
    }
}

extern "C" void kernel_launch(void* const* d_in, const int* in_sizes, int n_in,
                              void* d_out, int out_size, void* d_ws, size_t ws_size,
                              hipStream_t stream) {
    const float* x      = (const float*)d_in[0];
    const float* ln1_g  = (const float*)d_in[1];
    const float* ln1_b  = (const float*)d_in[2];
    const float* w_qkv  = (const float*)d_in[3];
    const float* w_proj = (const float*)d_in[4];
    const float* b_proj = (const float*)d_in[5];
    const float* ln2_g  = (const float*)d_in[6];
    const float* ln2_b  = (const float*)d_in[7];
    const float* w_fc1  = (const float*)d_in[8];
    const float* b_fc1  = (const float*)d_in[9];
    const float* w_fc2  = (const float*)d_in[10];
    const float* b_fc2  = (const float*)d_in[11];
    float* out = (float*)d_out;

    char* ws = (char*)d_ws;
    auto al = [](size_t b){ return (b + 255) & ~(size_t)255; };
    size_t off = 0;
    auto take = [&](size_t b)->char* { char* p = ws + off; off += al(b); return p; };

    bf16* wqkvT  = (bf16*)take((size_t)2304 * 768 * 2);
    bf16* wprojT = (bf16*)take((size_t)768 * 768 * 2);
    bf16* wfc1T  = (bf16*)take((size_t)3072 * 768 * 2);
    bf16* wfc2T  = (bf16*)take((size_t)768 * 3072 * 2);
    bf16* h      = (bf16*)take((size_t)MPAD * CEMB * 2);
    bf16* o      = (bf16*)take((size_t)MPAD * CEMB * 2);
    size_t fixedEnd = off;

    const size_t qkvB = (size_t)NBH * NP * HDIM * 2;
    bf16* q_c  = (bf16*)(ws + fixedEnd);
    bf16* k_c  = (bf16*)(ws + fixedEnd + qkvB);
    bf16* vT_c = (bf16*)(ws + fixedEnd + 2 * qkvB);
    bf16* g_c  = (bf16*)(ws + fixedEnd);       // MLP reuses region

    transpose_w<<<(768 * 2304 + 255) / 256, 256, 0, stream>>>(w_qkv, wqkvT, 768, 2304);
    transpose_w<<<(768 * 768 + 255) / 256, 256, 0, stream>>>(w_proj, wprojT, 768, 768);
    transpose_w<<<(768 * 3072 + 255) / 256, 256, 0, stream>>>(w_fc1, wfc1T, 768, 3072);
    transpose_w<<<(3072 * 768 + 255) / 256, 256, 0, stream>>>(w_fc2, wfc2T, 3072, 768);

    ln_kernel<<<NTOK, 256, 0, stream>>>(x, ln1_g, ln1_b, h);

    {
        GemmParams p{};
        p.A = h; p.Bt = wqkvT;
        p.M = MPAD; p.N = 3 * CEMB; p.K = CEMB; p.Mreal = NTOK;
        p.qb = q_c; p.kb = k_c; p.vtb = vT_c;
        gemm256<MODE_QKV><<<dim3(MPAD / 256, 3 * CEMB / 128), 512, 0, stream>>>(p);
    }

    flash_attn<<<dim3(NP / 128, NBH), 256, 0, stream>>>(q_c, k_c, vT_c, o);

    {
        GemmParams p{};
        p.A = o; p.Bt = wprojT;
        p.M = MPAD; p.N = CEMB; p.K = CEMB; p.Mreal = NTOK;
        p.Cf = out; p.bias = b_proj; p.resid = x;
        gemm256<MODE_PROJ><<<dim3(MPAD / 256, CEMB / 128), 512, 0, stream>>>(p);
    }

    ln_kernel<<<NTOK, 256, 0, stream>>>(out, ln2_g, ln2_b, h);

    {
        GemmParams p{};
        p.A = h; p.Bt = wfc1T;
        p.M = MPAD; p.N = CHID; p.K = CEMB; p.Mreal = NTOK;
        p.Cb = g_c; p.bias = b_fc1;
        gemm256<MODE_FC1><<<dim3(MPAD / 256, CHID / 128), 512, 0, stream>>>(p);
    }

    {
        GemmParams p{};
        p.A = g_c; p.Bt = wfc2T;
        p.M = MPAD; p.N = CEMB; p.K = CHID; p.Mreal = NTOK;
        p.Cf = out; p.bias = b_fc2; p.resid = out;
        gemm256<MODE_FC2><<<dim3(MPAD / 256, CEMB / 128), 512, 0, stream>>>(p);
    }
}

// Round 21
// 1149.781 us; speedup vs baseline: 1.0850x; 1.0850x over previous
//
#include <hip/hip_runtime.h>
#include <hip/hip_bf16.h>
#include <math.h>

using bf16 = __hip_bfloat16;
typedef __attribute__((ext_vector_type(8))) short short8;
typedef __attribute__((ext_vector_type(4))) float f32x4;

#define NSEQ   577
#define NBATCH 64
#define NTOK   36928   // 64*577
#define MPAD   37120   // NTOK padded to multiple of 256
#define NHEADS 12
#define HDIM   64
#define NP     640     // padded seq len (multiple of 128)
#define CEMB   768
#define CHID   3072
#define NBH    (NBATCH*NHEADS)   // 768 head instances

__device__ __forceinline__ bf16 f2bf(float v){ return __float2bfloat16(v); }

// tanh-form GELU via one __expf; |err| vs exact ~1e-3, below bf16 rounding here.
__device__ __forceinline__ float gelu_f(float x) {
    float x3 = x * x * x;
    float y = 1.5957691216057308f * (x + 0.044715f * x3);
    float e = __expf(y);
    float t = 1.0f - 2.0f / (e + 1.0f);
    return 0.5f * x * (1.0f + t);
}

#define GLOAD_LDS16(gaddr, laddr) \
  __builtin_amdgcn_global_load_lds((__attribute__((address_space(1))) const void*)(gaddr), \
                                   (__attribute__((address_space(3))) void*)(laddr), 16, 0, 0)

// ---------------- weight convert+transpose: src fp32 [R][C] -> dst bf16 [C][R]
__global__ __launch_bounds__(256) void transpose_w(const float* __restrict__ src,
                                                   bf16* __restrict__ dst, int R, int C) {
    long idx = (long)blockIdx.x * 256 + threadIdx.x;
    long total = (long)R * C;
    if (idx < total) {
        int r = (int)(idx / C);
        int c = (int)(idx - (long)r * C);
        dst[(long)c * R + r] = f2bf(src[idx]);
    }
}

// ---------------- LayerNorm: fp32 [rows][768] -> bf16 [rows][768]
__global__ __launch_bounds__(256) void ln_kernel(const float* __restrict__ x,
                                                 const float* __restrict__ gamma,
                                                 const float* __restrict__ beta,
                                                 bf16* __restrict__ out) {
    int row = blockIdx.x;
    const float* xr = x + (size_t)row * CEMB;
    int tid = threadIdx.x;
    float v0 = xr[tid], v1 = xr[tid + 256], v2 = xr[tid + 512];
    float s = v0 + v1 + v2;
    #pragma unroll
    for (int o = 32; o > 0; o >>= 1) s += __shfl_down(s, o);
    __shared__ float red[4];
    if ((tid & 63) == 0) red[tid >> 6] = s;
    __syncthreads();
    float mean = (red[0] + red[1] + red[2] + red[3]) * (1.0f / CEMB);
    float d0 = v0 - mean, d1 = v1 - mean, d2 = v2 - mean;
    float q = d0*d0 + d1*d1 + d2*d2;
    #pragma unroll
    for (int o = 32; o > 0; o >>= 1) q += __shfl_down(q, o);
    __shared__ float red2[4];
    if ((tid & 63) == 0) red2[tid >> 6] = q;
    __syncthreads();
    float var = (red2[0] + red2[1] + red2[2] + red2[3]) * (1.0f / CEMB);
    float rs = rsqrtf(var + 1e-5f);
    bf16* orow = out + (size_t)row * CEMB;
    orow[tid]       = f2bf(d0 * rs * gamma[tid]       + beta[tid]);
    orow[tid + 256] = f2bf(d1 * rs * gamma[tid + 256] + beta[tid + 256]);
    orow[tid + 512] = f2bf(d2 * rs * gamma[tid + 512] + beta[tid + 512]);
}

// ---------------- fused flash attention (session-best r17/r19 version) --------
__global__ __launch_bounds__(256) void flash_attn(const bf16* __restrict__ qg,
                                                  const bf16* __restrict__ kg,
                                                  const bf16* __restrict__ vtg,
                                                  bf16* __restrict__ og) {
    const int tid = threadIdx.x, lane = tid & 63, w = tid >> 6;
    const int fr = lane & 15, fh = lane >> 4;

    // bijective XCD swizzle: all 5 q-blocks of a head land on one XCD's L2.
    const int QB = NP / 128;                      // 5
    const int nwg = QB * NBH;                     // 3840, %8 == 0
    const int lin = blockIdx.y * QB + blockIdx.x;
    const int qq = nwg >> 3;
    const int lin2 = (lin & 7) * qq + (lin >> 3);
    const int bh = lin2 / QB;
    const int q0 = (lin2 - bh * QB) * 128;
    const int wr = w * 32;

    __shared__ bf16 Ks[2][64 * 64];
    __shared__ bf16 Vs[2][64 * 64];
    __shared__ bf16 Ps[128 * 64];

    const bf16* qb = qg  + (size_t)bh * NP * HDIM;
    const bf16* kb = kg  + (size_t)bh * NP * HDIM;
    const bf16* vb = vtg + (size_t)bh * HDIM * NP;

    const int swz  = (fr & 7) << 3;
    const int scol = (((lane & 7) ^ (lane >> 3)) << 3);
    const int srow = lane >> 3;

    short8 qa[2][2];
    #pragma unroll
    for (int mi = 0; mi < 2; mi++)
        #pragma unroll
        for (int ks = 0; ks < 2; ks++)
            qa[mi][ks] = *reinterpret_cast<const short8*>(
                qb + (size_t)(q0 + wr + mi * 16 + fr) * HDIM + ks * 32 + fh * 8);
    #pragma unroll
    for (int mi = 0; mi < 2; mi++)
        #pragma unroll
        for (int ks = 0; ks < 2; ks++)
            asm volatile("" : "+v"(qa[mi][ks]));

    f32x4 od[2][4] = {};
    float m_run[2] = {-1e30f, -1e30f};
    float l_run[2] = {0.f, 0.f};

    auto stageKV = [&](int buf, int kb0) {
        GLOAD_LDS16(kb + (size_t)(kb0 + w * 8 + srow) * HDIM + scol,      Ks[buf] + w * 512);
        GLOAD_LDS16(kb + (size_t)(kb0 + 32 + w * 8 + srow) * HDIM + scol, Ks[buf] + 2048 + w * 512);
        GLOAD_LDS16(vb + (size_t)(w * 8 + srow) * NP + kb0 + scol,        Vs[buf] + w * 512);
        GLOAD_LDS16(vb + (size_t)(32 + w * 8 + srow) * NP + kb0 + scol,   Vs[buf] + 2048 + w * 512);
    };

    auto tileBody = [&](int buf, int kb0) {
        f32x4 sacc[2][4] = {};
        short8 kf[4][2];
        #pragma unroll
        for (int n = 0; n < 4; n++)
            #pragma unroll
            for (int ks = 0; ks < 2; ks++)
                kf[n][ks] = *reinterpret_cast<const short8*>(
                    &Ks[buf][(n * 16 + fr) * 64 + ((ks * 32 + fh * 8) ^ swz)]);
        __builtin_amdgcn_s_setprio(1);
        #pragma unroll
        for (int mi = 0; mi < 2; mi++)
            #pragma unroll
            for (int n = 0; n < 4; n++)
                #pragma unroll
                for (int ks = 0; ks < 2; ks++)
                    sacc[mi][n] = __builtin_amdgcn_mfma_f32_16x16x32_bf16(kf[n][ks], qa[mi][ks], sacc[mi][n], 0, 0, 0);
        __builtin_amdgcn_s_setprio(0);

        #pragma unroll
        for (int mi = 0; mi < 2; mi++) {
            float sv[4][4];
            float tm = -1e30f;
            #pragma unroll
            for (int n = 0; n < 4; n++)
                #pragma unroll
                for (int r = 0; r < 4; r++) {
                    int key = kb0 + n * 16 + fh * 4 + r;
                    float s = sacc[mi][n][r];
                    sv[n][r] = (key < NSEQ) ? s : -1e30f;
                    tm = fmaxf(tm, sv[n][r]);
                }
            tm = fmaxf(tm, __shfl_xor(tm, 16));
            tm = fmaxf(tm, __shfl_xor(tm, 32));
            float mo = m_run[mi];
            if (__any(tm - mo > 8.f)) {
                float mn = fmaxf(mo, tm);
                float sc = __expf(mo - mn);
                m_run[mi] = mn;
                l_run[mi] *= sc;
                #pragma unroll
                for (int r = 0; r < 4; r++) {
                    float s2 = __shfl(sc, fh * 4 + r);
                    #pragma unroll
                    for (int n2 = 0; n2 < 4; n2++) od[mi][n2][r] *= s2;
                }
                mo = mn;
            }
            float ps = 0.f;
            #pragma unroll
            for (int n = 0; n < 4; n++)
                #pragma unroll
                for (int r = 0; r < 4; r++) {
                    float e = __expf(sv[n][r] - mo);
                    sv[n][r] = e; ps += e;
                }
            ps += __shfl_xor(ps, 16);
            ps += __shfl_xor(ps, 32);
            l_run[mi] += ps;
            const int q = wr + mi * 16 + fr;
            char* prow = (char*)(Ps + q * 64);
            #pragma unroll
            for (int n = 0; n < 4; n++) {
                bf16 b0 = f2bf(sv[n][0]), b1 = f2bf(sv[n][1]);
                bf16 b2 = f2bf(sv[n][2]), b3 = f2bf(sv[n][3]);
                unsigned int lo = (unsigned int)*(unsigned short*)&b0 |
                                  ((unsigned int)*(unsigned short*)&b1 << 16);
                unsigned int hi = (unsigned int)*(unsigned short*)&b2 |
                                  ((unsigned int)*(unsigned short*)&b3 << 16);
                int chunk = (2 * n + (fh >> 1)) ^ (fr & 7);
                uint2 pk; pk.x = lo; pk.y = hi;
                *reinterpret_cast<uint2*>(prow + (chunk << 4) + ((fh & 1) << 3)) = pk;
            }
        }
        asm volatile("s_waitcnt lgkmcnt(0)" ::: "memory");
        __builtin_amdgcn_sched_barrier(0);

        short8 pa[2][2], vf[4][2];
        #pragma unroll
        for (int mi = 0; mi < 2; mi++)
            #pragma unroll
            for (int ks = 0; ks < 2; ks++)
                pa[mi][ks] = *reinterpret_cast<const short8*>(
                    &Ps[(wr + mi * 16 + fr) * 64 + ((ks * 32 + fh * 8) ^ swz)]);
        #pragma unroll
        for (int n2 = 0; n2 < 4; n2++)
            #pragma unroll
            for (int ks = 0; ks < 2; ks++)
                vf[n2][ks] = *reinterpret_cast<const short8*>(
                    &Vs[buf][(n2 * 16 + fr) * 64 + ((ks * 32 + fh * 8) ^ swz)]);
        __builtin_amdgcn_s_setprio(1);
        #pragma unroll
        for (int mi = 0; mi < 2; mi++)
            #pragma unroll
            for (int n2 = 0; n2 < 4; n2++)
                #pragma unroll
                for (int ks = 0; ks < 2; ks++)
                    od[mi][n2] = __builtin_amdgcn_mfma_f32_16x16x32_bf16(pa[mi][ks], vf[n2][ks], od[mi][n2], 0, 0, 0);
        __builtin_amdgcn_s_setprio(0);
    };

    stageKV(0, 0);
    stageKV(1, 64);
    for (int t = 0; t < 9; ++t) {
        asm volatile("s_waitcnt vmcnt(4)" ::: "memory");
        __builtin_amdgcn_s_barrier();
        tileBody(t & 1, t * 64);
        asm volatile("s_waitcnt lgkmcnt(0)" ::: "memory");
        __builtin_amdgcn_s_barrier();
        if (t + 2 < 10) stageKV(t & 1, (t + 2) * 64);
    }
    asm volatile("s_waitcnt vmcnt(0)" ::: "memory");
    __builtin_amdgcn_s_barrier();
    tileBody(1, 9 * 64);

    const int b = bh / NHEADS, hh = bh - b * NHEADS;
    #pragma unroll
    for (int mi = 0; mi < 2; mi++)
        #pragma unroll
        for (int r = 0; r < 4; r++) {
            float lv = __shfl(l_run[mi], fh * 4 + r);
            int qrow = q0 + wr + mi * 16 + fh * 4 + r;
            if (qrow < NSEQ) {
                float inv = 1.f / lv;
                #pragma unroll
                for (int n2 = 0; n2 < 4; n2++)
                    og[((size_t)(b * NSEQ + qrow)) * CEMB + hh * HDIM + n2 * 16 + fr] =
                        f2bf(od[mi][n2][r] * inv);
            }
        }
}

// ---------------- 256x128 tile, BK=32, 8 waves (4Mx2N), 2-phase 48KB dbuf
// Session-best GEMM (r17/r19): 16x16x32 MFMA, 0-conflict swizzle keys,
// A-major XCD chunking. All alternative schedules/shapes measured worse.
#define MODE_QKV  1
#define MODE_PROJ 3
#define MODE_FC1  4
#define MODE_FC2  5

struct GemmParams {
    const bf16* A;
    const bf16* Bt;
    int M, N, K;            // M %256==0, N %128==0; K%32==0
    int Mreal;
    float* Cf;
    bf16* Cb;
    const float* bias;
    const float* resid;
    bf16* qb; bf16* kb; bf16* vtb;
};

template<int MODE>
__global__ __launch_bounds__(512, 2) void gemm256(GemmParams p) {
    __shared__ bf16 As[2][256 * 32];   // 16 KB each, swizzle key (row>>1)&3
    __shared__ bf16 Bs[2][128 * 32];   // 8 KB each
    const int tid  = threadIdx.x;
    const int lane = tid & 63;

    const int gx = gridDim.x, gy = gridDim.y;
    const int nwg = gx * gy;
    const int orig = blockIdx.y * gx + blockIdx.x;
    const int q8 = nwg >> 3, r8 = nwg & 7;
    const int xcd = orig & 7, oid = orig >> 3;
    const int lin2 = ((xcd < r8) ? xcd * (q8 + 1) : r8 * (q8 + 1) + (xcd - r8) * q8) + oid;
    const int bm = (lin2 / gy) * 256;
    const int bn = (lin2 % gy) * 128;

    const int Kd = p.K;
    const int w  = tid >> 6;
    const int wm = w >> 1, wn = w & 1;   // 4M x 2N wave grid, per-wave 64x64
    const int wr = wm * 64, wc = wn * 64;
    const int fr = lane & 15;
    const int fh = lane >> 4;
    const int rswz = ((fh ^ ((fr >> 1) & 3)) << 3);   // verified 0-conflict key

    const int srowA = tid >> 2;
    const int scol  = (((tid & 3) ^ ((tid >> 3) & 3)) << 3);
    const bf16* aS0 = p.A  + (size_t)(bm + srowA) * Kd + scol;
    const bf16* aS1 = p.A  + (size_t)(bm + 128 + srowA) * Kd + scol;
    const bf16* bS  = p.Bt + (size_t)(bn + srowA) * Kd + scol;

    f32x4 acc[4][4] = {};

    auto stage = [&](int buf, int kt) {
        GLOAD_LDS16(aS0 + (size_t)kt * 32, As[buf] + (size_t)tid * 8);
        GLOAD_LDS16(aS1 + (size_t)kt * 32, As[buf] + (size_t)(tid + 512) * 8);
        GLOAD_LDS16(bS  + (size_t)kt * 32, Bs[buf] + (size_t)tid * 8);
    };
    auto compute = [&](int buf) {
        const bf16* Ad = As[buf]; const bf16* Bd = Bs[buf];
        short8 a[4], b[4];
        #pragma unroll
        for (int n = 0; n < 4; n++)
            b[n] = *reinterpret_cast<const short8*>(&Bd[(wc + n * 16 + fr) * 32 + rswz]);
        #pragma unroll
        for (int m = 0; m < 4; m++)
            a[m] = *reinterpret_cast<const short8*>(&Ad[(wr + m * 16 + fr) * 32 + rswz]);
        __builtin_amdgcn_s_setprio(1);
        #pragma unroll
        for (int m = 0; m < 4; m++)
            #pragma unroll
            for (int n = 0; n < 4; n++)
                acc[m][n] = __builtin_amdgcn_mfma_f32_16x16x32_bf16(a[m], b[n], acc[m][n], 0, 0, 0);
        __builtin_amdgcn_s_setprio(0);
    };

    const int T = Kd >> 5;
    stage(0, 0);
    __syncthreads();
    for (int t = 1; t < T; ++t) {
        stage(t & 1, t);
        compute((t - 1) & 1);
        __syncthreads();
    }
    compute((T - 1) & 1);

    const int fq = (lane >> 4) * 4;
    const int colw = bn + wc;

    if (MODE == MODE_QKV) {
        const int which = colw / CEMB;
        const int hh = (colw - which * CEMB) >> 6;
        const float scl = (which == 0) ? 0.125f : 1.0f;
        #pragma unroll
        for (int m = 0; m < 4; m++)
        #pragma unroll
        for (int r = 0; r < 4; r++) {
            int row = bm + wr + m * 16 + fq + r;
            if (row < p.Mreal) {
                int b2 = row / NSEQ;
                int n2 = row - b2 * NSEQ;
                size_t bh = (size_t)b2 * NHEADS + hh;
                if (which == 0) {
                    bf16* dst = p.qb + (bh * NP + n2) * HDIM + fr;
                    #pragma unroll
                    for (int n = 0; n < 4; n++) dst[n * 16] = f2bf(acc[m][n][r] * scl);
                } else if (which == 1) {
                    bf16* dst = p.kb + (bh * NP + n2) * HDIM + fr;
                    #pragma unroll
                    for (int n = 0; n < 4; n++) dst[n * 16] = f2bf(acc[m][n][r]);
                } else {
                    bf16* dst = p.vtb + (bh * HDIM + fr) * NP + n2;
                    #pragma unroll
                    for (int n = 0; n < 4; n++) dst[(size_t)n * 16 * NP] = f2bf(acc[m][n][r]);
                }
            }
        }
    } else if (MODE == MODE_FC1) {
        const float* bp = p.bias + colw + fr;
        float bb[4];
        #pragma unroll
        for (int n = 0; n < 4; n++) bb[n] = bp[n * 16];
        #pragma unroll
        for (int m = 0; m < 4; m++)
        #pragma unroll
        for (int r = 0; r < 4; r++) {
            int row = bm + wr + m * 16 + fq + r;
            if (row < p.Mreal) {
                bf16* crow = p.Cb + (size_t)row * p.N + colw + fr;
                #pragma unroll
                for (int n = 0; n < 4; n++)
                    crow[n * 16] = f2bf(gelu_f(acc[m][n][r] + bb[n]));
            }
        }
    } else {
        const float* bp = p.bias + colw + fr;
        float bb[4];
        #pragma unroll
        for (int n = 0; n < 4; n++) bb[n] = bp[n * 16];
        #pragma unroll
        for (int m = 0; m < 4; m++)
        #pragma unroll
        for (int r = 0; r < 4; r++) {
            int row = bm + wr + m * 16 + fq + r;
            if (row < p.Mreal) {
                float* crow = p.Cf + (size_t)row * p.N + colw + fr;
                const float* rrow = p.resid + (size_t)row * p.N + colw + fr;
                #pragma unroll
                for (int n = 0; n < 4; n++)
                    crow[n * 16] = acc[m][n][r] + bb[n] + rrow[n * 16];
            }
        }
    }
}

extern "C" void kernel_launch(void* const* d_in, const int* in_sizes, int n_in,
                              void* d_out, int out_size, void* d_ws, size_t ws_size,
                              hipStream_t stream) {
    const float* x      = (const float*)d_in[0];
    const float* ln1_g  = (const float*)d_in[1];
    const float* ln1_b  = (const float*)d_in[2];
    const float* w_qkv  = (const float*)d_in[3];
    const float* w_proj = (const float*)d_in[4];
    const float* b_proj = (const float*)d_in[5];
    const float* ln2_g  = (const float*)d_in[6];
    const float* ln2_b  = (const float*)d_in[7];
    const float* w_fc1  = (const float*)d_in[8];
    const float* b_fc1  = (const float*)d_in[9];
    const float* w_fc2  = (const float*)d_in[10];
    const float* b_fc2  = (const float*)d_in[11];
    float* out = (float*)d_out;

    char* ws = (char*)d_ws;
    auto al = [](size_t b){ return (b + 255) & ~(size_t)255; };
    size_t off = 0;
    auto take = [&](size_t b)->char* { char* p = ws + off; off += al(b); return p; };

    bf16* wqkvT  = (bf16*)take((size_t)2304 * 768 * 2);
    bf16* wprojT = (bf16*)take((size_t)768 * 768 * 2);
    bf16* wfc1T  = (bf16*)take((size_t)3072 * 768 * 2);
    bf16* wfc2T  = (bf16*)take((size_t)768 * 3072 * 2);
    bf16* h      = (bf16*)take((size_t)MPAD * CEMB * 2);
    bf16* o      = (bf16*)take((size_t)MPAD * CEMB * 2);
    size_t fixedEnd = off;

    const size_t qkvB = (size_t)NBH * NP * HDIM * 2;
    bf16* q_c  = (bf16*)(ws + fixedEnd);
    bf16* k_c  = (bf16*)(ws + fixedEnd + qkvB);
    bf16* vT_c = (bf16*)(ws + fixedEnd + 2 * qkvB);
    bf16* g_c  = (bf16*)(ws + fixedEnd);       // MLP reuses region

    transpose_w<<<(768 * 2304 + 255) / 256, 256, 0, stream>>>(w_qkv, wqkvT, 768, 2304);
    transpose_w<<<(768 * 768 + 255) / 256, 256, 0, stream>>>(w_proj, wprojT, 768, 768);
    transpose_w<<<(768 * 3072 + 255) / 256, 256, 0, stream>>>(w_fc1, wfc1T, 768, 3072);
    transpose_w<<<(3072 * 768 + 255) / 256, 256, 0, stream>>>(w_fc2, wfc2T, 3072, 768);

    ln_kernel<<<NTOK, 256, 0, stream>>>(x, ln1_g, ln1_b, h);

    {
        GemmParams p{};
        p.A = h; p.Bt = wqkvT;
        p.M = MPAD; p.N = 3 * CEMB; p.K = CEMB; p.Mreal = NTOK;
        p.qb = q_c; p.kb = k_c; p.vtb = vT_c;
        gemm256<MODE_QKV><<<dim3(MPAD / 256, 3 * CEMB / 128), 512, 0, stream>>>(p);
    }

    flash_attn<<<dim3(NP / 128, NBH), 256, 0, stream>>>(q_c, k_c, vT_c, o);

    {
        GemmParams p{};
        p.A = o; p.Bt = wprojT;
        p.M = MPAD; p.N = CEMB; p.K = CEMB; p.Mreal = NTOK;
        p.Cf = out; p.bias = b_proj; p.resid = x;
        gemm256<MODE_PROJ><<<dim3(MPAD / 256, CEMB / 128), 512, 0, stream>>>(p);
    }

    ln_kernel<<<NTOK, 256, 0, stream>>>(out, ln2_g, ln2_b, h);

    {
        GemmParams p{};
        p.A = h; p.Bt = wfc1T;
        p.M = MPAD; p.N = CHID; p.K = CEMB; p.Mreal = NTOK;
        p.Cb = g_c; p.bias = b_fc1;
        gemm256<MODE_FC1><<<dim3(MPAD / 256, CHID / 128), 512, 0, stream>>>(p);
    }

    {
        GemmParams p{};
        p.A = g_c; p.Bt = wfc2T;
        p.M = MPAD; p.N = CEMB; p.K = CHID; p.Mreal = NTOK;
        p.Cf = out; p.bias = b_fc2; p.resid = out;
        gemm256<MODE_FC2><<<dim3(MPAD / 256, CEMB / 128), 512, 0, stream>>>(p);
    }
}